// Round 7
// baseline (403.225 us; speedup 1.0000x reference)
//
#include <hip/hip_runtime.h>
#include <hip/hip_bf16.h>
#include <math.h>

// Problem constants (fixed dataset: n=100, k=5, q=75, d=4096)
#define NQUERY 7500
#define NCLS   100
#define DIM    4096
#define KQ     75
#define KSUP   5
#define RPC    80        // rows per class in x = k+q
#define MPAD   7552      // 472 m-tiles * 16
#define NPAD   112       // 7 n-tiles * 16
#define CAPQ   256
#define RCAP   2048
#define EPSF   1e-8f
#define SELEM  845824    // MPAD * NPAD
#define SLICE_BYTES 3383296u

typedef __attribute__((ext_vector_type(8))) short bf16x8;
typedef __attribute__((ext_vector_type(4))) short s16x4;
typedef __attribute__((ext_vector_type(4))) float f32x4;

__device__ __forceinline__ int xrow_of_query(int j) {
    return (j / KQ) * RPC + KSUP + (j % KQ);
}
__device__ __forceinline__ short bf16t(float x) {       // truncate fp32 -> bf16 bits
    union { float f; unsigned u; } v; v.f = x;
    return (short)(v.u >> 16);
}
// async global->LDS, 16 B per lane: HW scatters to (wave-uniform base) + lane*16
__device__ __forceinline__ void gload_lds16(const short* g, short* l) {
    __builtin_amdgcn_global_load_lds(
        (const __attribute__((address_space(1))) unsigned int*)g,
        (__attribute__((address_space(3))) unsigned int*)l, 16, 0, 0);
}

// tile-layout offset for class-column c, dim index i:
// [nt][kstep][kq][lm][8] with nt=c>>4, lm=c&15, kstep=i>>5, kq=(i>>3)&3, e=i&7
__device__ __forceinline__ size_t tile_off(int nt, int lm, int i) {
    return (((size_t)(nt * 128 + (i >> 5)) * 4 + ((i >> 3) & 3)) * 16 + lm) * 8 + (i & 7);
}

// stage the 7 n-tile chunks (1 KB each) of one kstep into LDS buf (4 waves share)
__device__ __forceinline__ void stageB(const short* __restrict__ Bt, int kstep,
        short* buf, int w, int lane) {
#pragma unroll
    for (int p = 0; p < 2; ++p) {
        const int cid = w * 2 + p;
        if (cid < 7) {
            const short* gsrc = Bt + ((size_t)(cid * 128 + kstep) << 9);
            gload_lds16(gsrc + lane * 8, buf + (cid << 9));
        }
    }
}

// ---------------- K1: fused proto: mean -> norm -> Phi tile layout + es
__global__ __launch_bounds__(256) void k_proto(const float* __restrict__ x,
        float* __restrict__ proto, short* __restrict__ Phi, float* __restrict__ es) {
    const int c = blockIdx.x, t = threadIdx.x;
    const int nt = c >> 4, lm = c & 15;
    if (c >= NCLS) {
        for (int g = t; g < 512; g += 256) {
            const int kstep = g >> 2, kq = g & 3;
            size_t o = (((size_t)(nt * 128 + kstep) * 4 + kq) * 16 + lm) * 8;
            bf16x8 z = {0,0,0,0,0,0,0,0};
            *(bf16x8*)(Phi + o) = z;
        }
        if (t == 0) es[c] = 0.f;
        return;
    }
    __shared__ float red[4];
    __shared__ float s_inv;
    const float* b0 = x + (size_t)(c * RPC) * DIM;
    float v[16];
    float ssq = 0.f;
#pragma unroll
    for (int p = 0; p < 4; ++p) {
        const int i = p * 1024 + t * 4;
        f32x4 s = {0.f, 0.f, 0.f, 0.f};
#pragma unroll
        for (int r = 0; r < KSUP; ++r)
            s += *(const f32x4*)(b0 + (size_t)r * DIM + i);
        s = s / 5.0f;
        *(f32x4*)&v[p*4] = s;
        *(f32x4*)(proto + (size_t)c*DIM + i) = s;
        ssq += s[0]*s[0] + s[1]*s[1] + s[2]*s[2] + s[3]*s[3];
    }
    for (int o = 32; o; o >>= 1) ssq += __shfl_down(ssq, o);
    if ((t & 63) == 0) red[t >> 6] = ssq;
    __syncthreads();
    if (t == 0) {
        float tot = red[0] + red[1] + red[2] + red[3];
        float inv = 1.f / fmaxf(sqrtf(tot), EPSF);
        s_inv = inv;
        es[c] = expf(tot * inv * inv);
    }
    __syncthreads();
    const float inv = s_inv;
#pragma unroll
    for (int p = 0; p < 4; ++p) {
        const int i = p * 1024 + t * 4;
        s16x4 h;
#pragma unroll
        for (int e = 0; e < 4; ++e) h[e] = bf16t(v[p*4+e] * inv);
        *(s16x4*)(Phi + tile_off(nt, lm, i)) = h;
    }
}

// ---------------- K2/K8: unified GEMM partials, bf16-hi, double-buffered LDS B
// grid (118, TNKS), block 256 = 4 waves, wave = one 16-row m-tile x 7 n-tiles
template<int TNKS, bool SSQ>
__global__ __launch_bounds__(256) void k_gemm(const float* __restrict__ x,
        const short* __restrict__ Bt, float* __restrict__ Part, float* __restrict__ nq2) {
    constexpr int KST = 128 / TNKS;   // ksteps (of 32) per block
    __shared__ short bbuf[2][7 * 512];  // 2 x 7 KB
    const int bx = blockIdx.x, kz = blockIdx.y;
    const int w = threadIdx.x >> 6, lane = threadIdx.x & 63;
    const int lm = lane & 15, kq = lane >> 4;
    const int mt = bx * 4 + w;
    const int j = mt * 16 + lm;
    const int jc = j < NQUERY ? j : NQUERY - 1;
    const float* pa = x + (size_t)xrow_of_query(jc) * DIM + kq * 8;
    const int ks0 = kz * KST;

    f32x4 acc[7];
#pragma unroll
    for (int nt = 0; nt < 7; ++nt) acc[nt] = (f32x4){0.f,0.f,0.f,0.f};
    float ssq = 0.f;

    // prologue: stage kstep ks0 + prefetch A
    stageB(Bt, ks0, bbuf[0], w, lane);
    f32x4 a0 = *(const f32x4*)(pa + ks0 * 32);
    f32x4 a1 = *(const f32x4*)(pa + ks0 * 32 + 4);
    __syncthreads();

#pragma unroll
    for (int s = 0; s < KST; ++s) {
        const int cur = s & 1;
        f32x4 n0 = a0, n1 = a1;
        if (s + 1 < KST) {
            stageB(Bt, ks0 + s + 1, bbuf[cur ^ 1], w, lane);   // async, other buffer
            n0 = *(const f32x4*)(pa + (ks0 + s + 1) * 32);     // A register prefetch
            n1 = *(const f32x4*)(pa + (ks0 + s + 1) * 32 + 4);
        }
        float fv[8] = {a0[0],a0[1],a0[2],a0[3],a1[0],a1[1],a1[2],a1[3]};
        bf16x8 ah;
#pragma unroll
        for (int e = 0; e < 8; ++e) {
            if (SSQ) ssq += fv[e] * fv[e];
            ah[e] = bf16t(fv[e]);
        }
#pragma unroll
        for (int nt = 0; nt < 7; ++nt) {
            const bf16x8 bh = *(const bf16x8*)(&bbuf[cur][(nt << 9) + lane * 8]);
            acc[nt] = __builtin_amdgcn_mfma_f32_16x16x32_bf16(ah, bh, acc[nt], 0, 0, 0);
        }
        __syncthreads();    // drains next-buffer staging; all waves done with cur
        a0 = n0; a1 = n1;
    }

    if (SSQ) {
        float s2 = ssq;
        s2 += __shfl_xor(s2, 16);
        s2 += __shfl_xor(s2, 32);
        if (kq == 0 && j < NQUERY) atomicAdd(&nq2[j], s2);
    }
    float* sp = Part + (size_t)kz * SELEM + (size_t)(mt * 16) * NPAD;
#pragma unroll
    for (int nt = 0; nt < 7; ++nt)
#pragma unroll
        for (int r = 0; r < 4; ++r)
            sp[(size_t)(kq * 4 + r) * NPAD + nt * 16 + lm] = acc[nt][r];
}

// ---------------- K2b: Sred = sum over kz slices
__global__ __launch_bounds__(256) void k_reduce1(const float* __restrict__ Spart,
        float* __restrict__ Sred, int nks) {
    const int idx = blockIdx.x * 256 + threadIdx.x;   // < 211456
    const size_t e = (size_t)idx * 4;
    f32x4 s = {0.f, 0.f, 0.f, 0.f};
    for (int kz = 0; kz < nks; ++kz)
        s += *(const f32x4*)(Spart + (size_t)kz * SELEM + e);
    *(f32x4*)(Sred + e) = s;
}

// ---------------- K3: argmax/top2 + invq + coef + per-class lists + refine-list
__global__ __launch_bounds__(256) void k_argmax(const float* __restrict__ S,
        const float* __restrict__ nq2, float* __restrict__ coef, float* __restrict__ invq,
        int* __restrict__ pos, int* __restrict__ ccnt, int* __restrict__ cls_list,
        int* __restrict__ rcnt, int* __restrict__ rlist) {
    const int j = blockIdx.x * 256 + threadIdx.x;
    if (j >= NQUERY) return;
    const float* row = S + (size_t)j * NPAD;
    float m1 = -1e30f, m2 = -1e30f;
    int i1 = 0, i2 = 0;
    for (int c = 0; c < NCLS; ++c) {
        float v = row[c];
        if (v > m1) { m2 = m1; i2 = i1; m1 = v; i1 = c; }
        else if (v > m2) { m2 = v; i2 = c; }
    }
    const float inv = 1.f / fmaxf(sqrtf(nq2[j]), EPSF);
    invq[j] = inv;
    coef[j] = expf(m1 * inv);
    const int p = atomicAdd(&ccnt[i1], 1);
    if (p < CAPQ) { cls_list[i1 * CAPQ + p] = j; pos[j] = p; }
    else pos[j] = -1;
    if ((m1 - m2) * inv < 5e-4f) {     // bf16-hi gap noise sigma ~5e-5 -> 10 sigma
        int rp = atomicAdd(rcnt, 1);
        if (rp < RCAP) rlist[rp] = j | (i1 << 13) | (i2 << 20);
    }
}

// ---------------- K4: fp64 refinement of borderline argmax; patches lists
__global__ __launch_bounds__(64) void k_refine(const float* __restrict__ x,
        const float* __restrict__ S, const float* __restrict__ invq,
        float* __restrict__ coef, const int* __restrict__ pos,
        int* __restrict__ ccnt, int* __restrict__ cls_list,
        const int* __restrict__ rcnt, const int* __restrict__ rlist) {
    const int cnt = min(*rcnt, RCAP);
    const int lane = threadIdx.x;
    for (int e = blockIdx.x; e < cnt; e += gridDim.x) {
        const int pk = rlist[e];
        const int j = pk & 8191, c1 = (pk >> 13) & 127, c2 = (pk >> 20) & 127;
        const float* xq = x + (size_t)xrow_of_query(j) * DIM;
        const int cc[2] = {c1, c2};
        double cosv[2];
#pragma unroll
        for (int s = 0; s < 2; ++s) {
            const float* xb = x + (size_t)(cc[s] * RPC) * DIM;
            double dt = 0.0, pp = 0.0, q2 = 0.0;
            for (int i = lane; i < DIM; i += 64) {
                double p = (double)xb[i] + (double)xb[i + DIM] + (double)xb[i + 2*DIM]
                         + (double)xb[i + 3*DIM] + (double)xb[i + 4*DIM];
                double qv = (double)xq[i];
                dt += p * qv; pp += p * p; q2 += qv * qv;
            }
            for (int o = 32; o; o >>= 1) {
                dt += __shfl_down(dt, o);
                pp += __shfl_down(pp, o);
                q2 += __shfl_down(q2, o);
            }
            cosv[s] = dt / (sqrt(pp) * sqrt(q2));
        }
        if (lane == 0) {
            int win = (cosv[1] > cosv[0] || (cosv[1] == cosv[0] && c2 < c1)) ? c2 : c1;
            if (win != c1) {
                coef[j] = expf(S[(size_t)j * NPAD + win] * invq[j]);
                const int pj = pos[j];
                if (pj >= 0) cls_list[c1 * CAPQ + pj] = -1;   // tombstone
                const int np = atomicAdd(&ccnt[c2], 1);
                if (np < CAPQ) cls_list[c2 * CAPQ + np] = j;
            }
        }
    }
}

// ---------------- K6: adapted-proto partial scatter sum (grid 8 x NCLS x 4)
__global__ __launch_bounds__(128) void k_adapt(const float* __restrict__ x,
        const float* __restrict__ coef, const int* __restrict__ cls_cnt,
        const int* __restrict__ cls_list, float* __restrict__ APpart) {
    const int cx = blockIdx.x, c = blockIdx.y, sl = blockIdx.z;
    const int i0 = cx * 512 + threadIdx.x * 4;
    const int n = min(cls_cnt[c], CAPQ);
    f32x4 acc = {0.f, 0.f, 0.f, 0.f};
    for (int e = sl; e < n; e += 4) {
        const int j = cls_list[c * CAPQ + e];
        if (j >= 0) {
            const float cf = coef[j];
            const f32x4 v = *(const f32x4*)(x + (size_t)xrow_of_query(j) * DIM + i0);
            acc += v * cf;
        }
    }
    *(f32x4*)(APpart + (size_t)sl * NCLS * DIM + (size_t)c * DIM + i0) = acc;
}

// ---------------- K7: fused apnorm: sum 4 slices + es*proto -> norm -> APhi tile layout
__global__ __launch_bounds__(256) void k_apnorm(const float* __restrict__ APpart,
        const float* __restrict__ proto, const float* __restrict__ es,
        short* __restrict__ APhi) {
    const int c = blockIdx.x, t = threadIdx.x;
    const int nt = c >> 4, lm = c & 15;
    if (c >= NCLS) {
        for (int g = t; g < 512; g += 256) {
            const int kstep = g >> 2, kq = g & 3;
            size_t o = (((size_t)(nt * 128 + kstep) * 4 + kq) * 16 + lm) * 8;
            bf16x8 z = {0,0,0,0,0,0,0,0};
            *(bf16x8*)(APhi + o) = z;
        }
        return;
    }
    __shared__ float red[4];
    __shared__ float s_inv;
    const float e0 = es[c];
    float v[16];
    float ssq = 0.f;
#pragma unroll
    for (int p = 0; p < 4; ++p) {
        const int i = p * 1024 + t * 4;
        f32x4 s = {0.f, 0.f, 0.f, 0.f};
#pragma unroll
        for (int sl = 0; sl < 4; ++sl)
            s += *(const f32x4*)(APpart + (size_t)sl * NCLS * DIM + (size_t)c * DIM + i);
        f32x4 pr = *(const f32x4*)(proto + (size_t)c*DIM + i);
        s += pr * e0;
        *(f32x4*)&v[p*4] = s;
        ssq += s[0]*s[0] + s[1]*s[1] + s[2]*s[2] + s[3]*s[3];
    }
    for (int o = 32; o; o >>= 1) ssq += __shfl_down(ssq, o);
    if ((t & 63) == 0) red[t >> 6] = ssq;
    __syncthreads();
    if (t == 0) {
        float tot = red[0] + red[1] + red[2] + red[3];
        s_inv = 1.f / fmaxf(sqrtf(tot), EPSF);
    }
    __syncthreads();
    const float inv = s_inv;
#pragma unroll
    for (int p = 0; p < 4; ++p) {
        const int i = p * 1024 + t * 4;
        s16x4 h;
#pragma unroll
        for (int e = 0; e < 4; ++e) h[e] = bf16t(v[p*4+e] * inv);
        *(s16x4*)(APhi + tile_off(nt, lm, i)) = h;
    }
}

// ---------------- K8b: out[j,c<100] = tao * invq[j] * sum_kz Opart
__global__ __launch_bounds__(256) void k_reduce2(const float* __restrict__ Opart,
        const float* __restrict__ invq, const float* __restrict__ tao,
        float* __restrict__ out, int nks) {
    const int idx = blockIdx.x * 256 + threadIdx.x;   // < 187500
    if (idx >= NQUERY * 25) return;
    const int j = idx / 25, c4 = (idx % 25) * 4;
    const size_t e = (size_t)j * NPAD + c4;
    f32x4 s = {0.f, 0.f, 0.f, 0.f};
    for (int kz = 0; kz < nks; ++kz)
        s += *(const f32x4*)(Opart + (size_t)kz * SELEM + e);
    const float sc = tao[0] * invq[j];
    *(f32x4*)(out + (size_t)j * NCLS + c4) = s * sc;
}

// ---------------- workspace layout (bytes)
#define OFF_RCNT   0u
#define OFF_CCNT   256u
#define OFF_NQ2    1792u        // 30000
#define ZERO_BYTES 32768u
#define OFF_ES     32768u
#define OFF_INVQ   33280u
#define OFF_POS    63488u
#define OFF_COEF   93696u
#define OFF_RLIST  123904u
#define OFF_CLIST  132096u      // 102400
#define OFF_PROTO  234496u      // 1,638,400
#define OFF_PHI    1872896u     // 917,504 (tile layout)
#define OFF_APHI   3707904u     // 917,504
#define OFF_SRED   4625408u     // 3,383,296
#define OFF_APPART 8008704u     // 4 x 1,638,400
#define OFF_PART   14562304u    // + nks x 3,383,296

extern "C" void kernel_launch(void* const* d_in, const int* in_sizes, int n_in,
                              void* d_out, int out_size, void* d_ws, size_t ws_size,
                              hipStream_t stream) {
    const float* x   = (const float*)d_in[0];
    const float* tao = (const float*)d_in[1];
    char* ws = (char*)d_ws;

    int*   rcnt    = (int*)  (ws + OFF_RCNT);
    int*   ccnt    = (int*)  (ws + OFF_CCNT);
    float* nq2     = (float*)(ws + OFF_NQ2);
    float* es      = (float*)(ws + OFF_ES);
    float* invq    = (float*)(ws + OFF_INVQ);
    int*   pos     = (int*)  (ws + OFF_POS);
    float* coef    = (float*)(ws + OFF_COEF);
    int*   rlist   = (int*)  (ws + OFF_RLIST);
    int*   clist   = (int*)  (ws + OFF_CLIST);
    float* proto   = (float*)(ws + OFF_PROTO);
    short* Phi     = (short*)(ws + OFF_PHI);
    short* APhi    = (short*)(ws + OFF_APHI);
    float* Sred    = (float*)(ws + OFF_SRED);
    float* APpart  = (float*)(ws + OFF_APPART);
    float* Part    = (float*)(ws + OFF_PART);

    // runtime k-split count from available scratch (pow2, 1..16)
    int nks = 1;
    if (ws_size > (size_t)OFF_PART + SLICE_BYTES) {
        size_t avail = (ws_size - OFF_PART) / SLICE_BYTES;
        nks = avail >= 16 ? 16 : (int)avail;
        while (nks & (nks - 1)) nks &= nks - 1;
    }

    hipMemsetAsync(ws, 0, ZERO_BYTES, stream);

    k_proto <<<NPAD, 256, 0, stream>>>(x, proto, Phi, es);
    switch (nks) {
        case 16: k_gemm<16,true><<<dim3(118, 16), 256, 0, stream>>>(x, Phi, Part, nq2); break;
        case 8:  k_gemm<8, true><<<dim3(118, 8),  256, 0, stream>>>(x, Phi, Part, nq2); break;
        case 4:  k_gemm<4, true><<<dim3(118, 4),  256, 0, stream>>>(x, Phi, Part, nq2); break;
        case 2:  k_gemm<2, true><<<dim3(118, 2),  256, 0, stream>>>(x, Phi, Part, nq2); break;
        default: k_gemm<1, true><<<dim3(118, 1),  256, 0, stream>>>(x, Phi, Part, nq2); break;
    }
    k_reduce1<<<826, 256, 0, stream>>>(Part, Sred, nks);
    k_argmax <<<30, 256, 0, stream>>>(Sred, nq2, coef, invq, pos, ccnt, clist, rcnt, rlist);
    k_refine <<<512, 64, 0, stream>>>(x, Sred, invq, coef, pos, ccnt, clist, rcnt, rlist);
    k_adapt  <<<dim3(8, NCLS, 4), 128, 0, stream>>>(x, coef, ccnt, clist, APpart);
    k_apnorm <<<NPAD, 256, 0, stream>>>(APpart, proto, es, APhi);
    switch (nks) {
        case 16: k_gemm<16,false><<<dim3(118, 16), 256, 0, stream>>>(x, APhi, Part, nq2); break;
        case 8:  k_gemm<8, false><<<dim3(118, 8),  256, 0, stream>>>(x, APhi, Part, nq2); break;
        case 4:  k_gemm<4, false><<<dim3(118, 4),  256, 0, stream>>>(x, APhi, Part, nq2); break;
        case 2:  k_gemm<2, false><<<dim3(118, 2),  256, 0, stream>>>(x, APhi, Part, nq2); break;
        default: k_gemm<1, false><<<dim3(118, 1),  256, 0, stream>>>(x, APhi, Part, nq2); break;
    }
    k_reduce2<<<733, 256, 0, stream>>>(Part, invq, tao, (float*)d_out, nks);
}

// Round 8
// 323.981 us; speedup vs baseline: 1.2446x; 1.2446x over previous
//
#include <hip/hip_runtime.h>
#include <hip/hip_bf16.h>
#include <math.h>

// Problem constants (fixed dataset: n=100, k=5, q=75, d=4096)
#define NQUERY 7500
#define NCLS   100
#define DIM    4096
#define KQ     75
#define KSUP   5
#define RPC    80        // rows per class in x = k+q
#define MPAD   7552      // 472 m-tiles * 16
#define NPAD   112       // 7 n-tiles * 16
#define CAPQ   256
#define RCAP   2048
#define EPSF   1e-8f
#define SELEM  845824    // MPAD * NPAD
#define SLICE_BYTES 3383296u

typedef __attribute__((ext_vector_type(8))) short bf16x8;
typedef __attribute__((ext_vector_type(4))) short s16x4;
typedef __attribute__((ext_vector_type(4))) float f32x4;

__device__ __forceinline__ int xrow_of_query(int j) {
    return (j / KQ) * RPC + KSUP + (j % KQ);
}
__device__ __forceinline__ short bf16t(float x) {       // truncate fp32 -> bf16 bits
    union { float f; unsigned u; } v; v.f = x;
    return (short)(v.u >> 16);
}
// async global->LDS, 16 B per lane: HW scatters to (wave-uniform base) + lane*16
__device__ __forceinline__ void gload_lds16(const short* g, short* l) {
    __builtin_amdgcn_global_load_lds(
        (const __attribute__((address_space(1))) unsigned int*)g,
        (__attribute__((address_space(3))) unsigned int*)l, 16, 0, 0);
}

// tile-layout offset for class-column c, dim index i:
// [nt][kstep][kq][lm][8] with nt=c>>4, lm=c&15, kstep=i>>5, kq=(i>>3)&3, e=i&7
__device__ __forceinline__ size_t tile_off(int nt, int lm, int i) {
    return (((size_t)(nt * 128 + (i >> 5)) * 4 + ((i >> 3) & 3)) * 16 + lm) * 8 + (i & 7);
}

// stage the 7 n-tile chunks (1 KB each) of one kstep into LDS buf (4 waves share)
__device__ __forceinline__ void stageB(const short* __restrict__ Bt, int kstep,
        short* buf, int w, int lane) {
#pragma unroll
    for (int p = 0; p < 2; ++p) {
        const int cid = w * 2 + p;
        if (cid < 7) {
            const short* gsrc = Bt + ((size_t)(cid * 128 + kstep) << 9);
            gload_lds16(gsrc + lane * 8, buf + (cid << 9));
        }
    }
}

// ---------------- K1: fused proto: mean -> norm (fp64) -> Phi tile layout + es + pninv
__global__ __launch_bounds__(256) void k_proto(const float* __restrict__ x,
        float* __restrict__ proto, short* __restrict__ Phi, float* __restrict__ es,
        double* __restrict__ pninv) {
    const int c = blockIdx.x, t = threadIdx.x;
    const int nt = c >> 4, lm = c & 15;
    if (c >= NCLS) {
        for (int g = t; g < 512; g += 256) {
            const int kstep = g >> 2, kq = g & 3;
            size_t o = (((size_t)(nt * 128 + kstep) * 4 + kq) * 16 + lm) * 8;
            bf16x8 z = {0,0,0,0,0,0,0,0};
            *(bf16x8*)(Phi + o) = z;
        }
        if (t == 0) es[c] = 0.f;
        return;
    }
    __shared__ double red[4];
    __shared__ float s_inv;
    const float* b0 = x + (size_t)(c * RPC) * DIM;
    float v[16];
    double ssq = 0.0;
#pragma unroll
    for (int p = 0; p < 4; ++p) {
        const int i = p * 1024 + t * 4;
        f32x4 s = {0.f, 0.f, 0.f, 0.f};
#pragma unroll
        for (int r = 0; r < KSUP; ++r)
            s += *(const f32x4*)(b0 + (size_t)r * DIM + i);
        s = s / 5.0f;
        *(f32x4*)&v[p*4] = s;
        *(f32x4*)(proto + (size_t)c*DIM + i) = s;
        ssq += (double)s[0]*s[0] + (double)s[1]*s[1]
             + (double)s[2]*s[2] + (double)s[3]*s[3];
    }
    for (int o = 32; o; o >>= 1) ssq += __shfl_down(ssq, o);
    if ((t & 63) == 0) red[t >> 6] = ssq;
    __syncthreads();
    if (t == 0) {
        double dtot = red[0] + red[1] + red[2] + red[3];
        pninv[c] = 1.0 / sqrt(dtot);
        float tot = (float)dtot;
        float inv = 1.f / fmaxf(sqrtf(tot), EPSF);
        s_inv = inv;
        es[c] = expf(tot * inv * inv);
    }
    __syncthreads();
    const float inv = s_inv;
#pragma unroll
    for (int p = 0; p < 4; ++p) {
        const int i = p * 1024 + t * 4;
        s16x4 h;
#pragma unroll
        for (int e = 0; e < 4; ++e) h[e] = bf16t(v[p*4+e] * inv);
        *(s16x4*)(Phi + tile_off(nt, lm, i)) = h;
    }
}

// ---------------- K2/K8: unified GEMM partials, bf16-hi, double-buffered LDS B
// grid (118, TNKS), block 256 = 4 waves, wave = one 16-row m-tile x 7 n-tiles
template<int TNKS, bool SSQ>
__global__ __launch_bounds__(256) void k_gemm(const float* __restrict__ x,
        const short* __restrict__ Bt, float* __restrict__ Part, float* __restrict__ nq2) {
    constexpr int KST = 128 / TNKS;   // ksteps (of 32) per block
    __shared__ short bbuf[2][7 * 512];  // 2 x 7 KB
    const int bx = blockIdx.x, kz = blockIdx.y;
    const int w = threadIdx.x >> 6, lane = threadIdx.x & 63;
    const int lm = lane & 15, kq = lane >> 4;
    const int mt = bx * 4 + w;
    const int j = mt * 16 + lm;
    const int jc = j < NQUERY ? j : NQUERY - 1;
    const float* pa = x + (size_t)xrow_of_query(jc) * DIM + kq * 8;
    const int ks0 = kz * KST;

    f32x4 acc[7];
#pragma unroll
    for (int nt = 0; nt < 7; ++nt) acc[nt] = (f32x4){0.f,0.f,0.f,0.f};
    float ssq = 0.f;

    // prologue: stage kstep ks0 + prefetch A
    stageB(Bt, ks0, bbuf[0], w, lane);
    f32x4 a0 = *(const f32x4*)(pa + ks0 * 32);
    f32x4 a1 = *(const f32x4*)(pa + ks0 * 32 + 4);
    __syncthreads();

#pragma unroll
    for (int s = 0; s < KST; ++s) {
        const int cur = s & 1;
        f32x4 n0 = a0, n1 = a1;
        if (s + 1 < KST) {
            stageB(Bt, ks0 + s + 1, bbuf[cur ^ 1], w, lane);   // async, other buffer
            n0 = *(const f32x4*)(pa + (ks0 + s + 1) * 32);     // A register prefetch
            n1 = *(const f32x4*)(pa + (ks0 + s + 1) * 32 + 4);
        }
        float fv[8] = {a0[0],a0[1],a0[2],a0[3],a1[0],a1[1],a1[2],a1[3]};
        bf16x8 ah;
#pragma unroll
        for (int e = 0; e < 8; ++e) {
            if (SSQ) ssq += fv[e] * fv[e];
            ah[e] = bf16t(fv[e]);
        }
#pragma unroll
        for (int nt = 0; nt < 7; ++nt) {
            const bf16x8 bh = *(const bf16x8*)(&bbuf[cur][(nt << 9) + lane * 8]);
            acc[nt] = __builtin_amdgcn_mfma_f32_16x16x32_bf16(ah, bh, acc[nt], 0, 0, 0);
        }
        __syncthreads();    // drains next-buffer staging; all waves done with cur
        a0 = n0; a1 = n1;
    }

    if (SSQ) {
        float s2 = ssq;
        s2 += __shfl_xor(s2, 16);
        s2 += __shfl_xor(s2, 32);
        if (kq == 0 && j < NQUERY) atomicAdd(&nq2[j], s2);
    }
    float* sp = Part + (size_t)kz * SELEM + (size_t)(mt * 16) * NPAD;
#pragma unroll
    for (int nt = 0; nt < 7; ++nt)
#pragma unroll
        for (int r = 0; r < 4; ++r)
            sp[(size_t)(kq * 4 + r) * NPAD + nt * 16 + lm] = acc[nt][r];
}

// ---------------- K2b: Sred = sum over kz slices
__global__ __launch_bounds__(256) void k_reduce1(const float* __restrict__ Spart,
        float* __restrict__ Sred, int nks) {
    const int idx = blockIdx.x * 256 + threadIdx.x;   // < 211456
    const size_t e = (size_t)idx * 4;
    f32x4 s = {0.f, 0.f, 0.f, 0.f};
    for (int kz = 0; kz < nks; ++kz)
        s += *(const f32x4*)(Spart + (size_t)kz * SELEM + e);
    *(f32x4*)(Sred + e) = s;
}

// ---------------- K3: argmax/top2 + invq + coef + per-class lists + refine-list
__global__ __launch_bounds__(256) void k_argmax(const float* __restrict__ S,
        const float* __restrict__ nq2, float* __restrict__ coef, float* __restrict__ invq,
        int* __restrict__ pos, int* __restrict__ ccnt, int* __restrict__ cls_list,
        int* __restrict__ rcnt, int* __restrict__ rlist) {
    const int j = blockIdx.x * 256 + threadIdx.x;
    if (j >= NQUERY) return;
    const float* row = S + (size_t)j * NPAD;
    float m1 = -1e30f, m2 = -1e30f;
    int i1 = 0, i2 = 0;
    for (int c = 0; c < NCLS; ++c) {
        float v = row[c];
        if (v > m1) { m2 = m1; i2 = i1; m1 = v; i1 = c; }
        else if (v > m2) { m2 = v; i2 = c; }
    }
    const float inv = 1.f / fmaxf(sqrtf(nq2[j]), EPSF);
    invq[j] = inv;
    coef[j] = expf(m1 * inv);
    const int p = atomicAdd(&ccnt[i1], 1);
    if (p < CAPQ) { cls_list[i1 * CAPQ + p] = j; pos[j] = p; }
    else pos[j] = -1;
    if ((m1 - m2) * inv < 5e-4f) {     // bf16-hi gap noise sigma ~5e-5 -> ~10 sigma
        int rp = atomicAdd(rcnt, 1);
        if (rp < RCAP) rlist[rp] = j | (i1 << 13) | (i2 << 20);
    }
}

// ---------------- K4: fp64 refinement via proto dot (query norm cancels; pninv precomputed)
// one 256-thread block per entry (grid-strided)
__global__ __launch_bounds__(256) void k_refine(const float* __restrict__ x,
        const float* __restrict__ proto, const double* __restrict__ pninv,
        const float* __restrict__ S, const float* __restrict__ invq,
        float* __restrict__ coef, const int* __restrict__ pos,
        int* __restrict__ ccnt, int* __restrict__ cls_list,
        const int* __restrict__ rcnt, const int* __restrict__ rlist) {
    const int cnt = min(*rcnt, RCAP);
    const int t = threadIdx.x;
    __shared__ double red1[4], red2[4];
    for (int e = blockIdx.x; e < cnt; e += gridDim.x) {
        const int pk = rlist[e];
        const int j = pk & 8191, c1 = (pk >> 13) & 127, c2 = (pk >> 20) & 127;
        const float* xq = x + (size_t)xrow_of_query(j) * DIM;
        const float* p1 = proto + (size_t)c1 * DIM;
        const float* p2 = proto + (size_t)c2 * DIM;
        double d1 = 0.0, d2 = 0.0;
        for (int i = t; i < DIM; i += 256) {
            const double qv = (double)xq[i];
            d1 += (double)p1[i] * qv;
            d2 += (double)p2[i] * qv;
        }
        for (int o = 32; o; o >>= 1) { d1 += __shfl_down(d1, o); d2 += __shfl_down(d2, o); }
        if ((t & 63) == 0) { red1[t >> 6] = d1; red2[t >> 6] = d2; }
        __syncthreads();
        if (t == 0) {
            const double cos1 = (red1[0]+red1[1]+red1[2]+red1[3]) * pninv[c1];
            const double cos2 = (red2[0]+red2[1]+red2[2]+red2[3]) * pninv[c2];
            const int win = (cos2 > cos1 || (cos2 == cos1 && c2 < c1)) ? c2 : c1;
            if (win != c1) {
                coef[j] = expf(S[(size_t)j * NPAD + win] * invq[j]);
                const int pj = pos[j];
                if (pj >= 0) cls_list[c1 * CAPQ + pj] = -1;   // tombstone
                const int np = atomicAdd(&ccnt[c2], 1);
                if (np < CAPQ) cls_list[c2 * CAPQ + np] = j;
            }
        }
        __syncthreads();   // red[] reuse across grid-stride iterations
    }
}

// ---------------- K6: adapted-proto partial scatter sum (grid 8 x NCLS x 4)
__global__ __launch_bounds__(128) void k_adapt(const float* __restrict__ x,
        const float* __restrict__ coef, const int* __restrict__ cls_cnt,
        const int* __restrict__ cls_list, float* __restrict__ APpart) {
    const int cx = blockIdx.x, c = blockIdx.y, sl = blockIdx.z;
    const int i0 = cx * 512 + threadIdx.x * 4;
    const int n = min(cls_cnt[c], CAPQ);
    f32x4 acc = {0.f, 0.f, 0.f, 0.f};
    for (int e = sl; e < n; e += 4) {
        const int j = cls_list[c * CAPQ + e];
        if (j >= 0) {
            const float cf = coef[j];
            const f32x4 v = *(const f32x4*)(x + (size_t)xrow_of_query(j) * DIM + i0);
            acc += v * cf;
        }
    }
    *(f32x4*)(APpart + (size_t)sl * NCLS * DIM + (size_t)c * DIM + i0) = acc;
}

// ---------------- K7: fused apnorm: sum 4 slices + es*proto -> norm -> APhi tile layout
__global__ __launch_bounds__(256) void k_apnorm(const float* __restrict__ APpart,
        const float* __restrict__ proto, const float* __restrict__ es,
        short* __restrict__ APhi) {
    const int c = blockIdx.x, t = threadIdx.x;
    const int nt = c >> 4, lm = c & 15;
    if (c >= NCLS) {
        for (int g = t; g < 512; g += 256) {
            const int kstep = g >> 2, kq = g & 3;
            size_t o = (((size_t)(nt * 128 + kstep) * 4 + kq) * 16 + lm) * 8;
            bf16x8 z = {0,0,0,0,0,0,0,0};
            *(bf16x8*)(APhi + o) = z;
        }
        return;
    }
    __shared__ float red[4];
    __shared__ float s_inv;
    const float e0 = es[c];
    float v[16];
    float ssq = 0.f;
#pragma unroll
    for (int p = 0; p < 4; ++p) {
        const int i = p * 1024 + t * 4;
        f32x4 s = {0.f, 0.f, 0.f, 0.f};
#pragma unroll
        for (int sl = 0; sl < 4; ++sl)
            s += *(const f32x4*)(APpart + (size_t)sl * NCLS * DIM + (size_t)c * DIM + i);
        f32x4 pr = *(const f32x4*)(proto + (size_t)c*DIM + i);
        s += pr * e0;
        *(f32x4*)&v[p*4] = s;
        ssq += s[0]*s[0] + s[1]*s[1] + s[2]*s[2] + s[3]*s[3];
    }
    for (int o = 32; o; o >>= 1) ssq += __shfl_down(ssq, o);
    if ((t & 63) == 0) red[t >> 6] = ssq;
    __syncthreads();
    if (t == 0) {
        float tot = red[0] + red[1] + red[2] + red[3];
        s_inv = 1.f / fmaxf(sqrtf(tot), EPSF);
    }
    __syncthreads();
    const float inv = s_inv;
#pragma unroll
    for (int p = 0; p < 4; ++p) {
        const int i = p * 1024 + t * 4;
        s16x4 h;
#pragma unroll
        for (int e = 0; e < 4; ++e) h[e] = bf16t(v[p*4+e] * inv);
        *(s16x4*)(APhi + tile_off(nt, lm, i)) = h;
    }
}

// ---------------- K8b: out[j,c<100] = tao * invq[j] * sum_kz Opart
__global__ __launch_bounds__(256) void k_reduce2(const float* __restrict__ Opart,
        const float* __restrict__ invq, const float* __restrict__ tao,
        float* __restrict__ out, int nks) {
    const int idx = blockIdx.x * 256 + threadIdx.x;   // < 187500
    if (idx >= NQUERY * 25) return;
    const int j = idx / 25, c4 = (idx % 25) * 4;
    const size_t e = (size_t)j * NPAD + c4;
    f32x4 s = {0.f, 0.f, 0.f, 0.f};
    for (int kz = 0; kz < nks; ++kz)
        s += *(const f32x4*)(Opart + (size_t)kz * SELEM + e);
    const float sc = tao[0] * invq[j];
    *(f32x4*)(out + (size_t)j * NCLS + c4) = s * sc;
}

// ---------------- workspace layout (bytes)
#define OFF_RCNT   0u
#define OFF_CCNT   256u
#define OFF_NQ2    1792u        // 30000
#define ZERO_BYTES 32768u
#define OFF_ES     32768u       // 448
#define OFF_INVQ   33280u       // 30000
#define OFF_POS    63488u       // 30000
#define OFF_COEF   93696u       // 30000
#define OFF_RLIST  123904u      // 8192
#define OFF_CLIST  132096u      // 102400
#define OFF_PNINV  234496u      // 800 (doubles)
#define OFF_PROTO  235520u      // 1,638,400
#define OFF_PHI    1873920u     // 917,504 (tile layout)
#define OFF_APHI   2791424u     // 917,504
#define OFF_SRED   3708928u     // 3,383,296
#define OFF_APPART 7092224u     // 4 x 1,638,400
#define OFF_PART   13645824u    // + nks x 3,383,296

extern "C" void kernel_launch(void* const* d_in, const int* in_sizes, int n_in,
                              void* d_out, int out_size, void* d_ws, size_t ws_size,
                              hipStream_t stream) {
    const float* x   = (const float*)d_in[0];
    const float* tao = (const float*)d_in[1];
    char* ws = (char*)d_ws;

    int*    rcnt    = (int*)   (ws + OFF_RCNT);
    int*    ccnt    = (int*)   (ws + OFF_CCNT);
    float*  nq2     = (float*) (ws + OFF_NQ2);
    float*  es      = (float*) (ws + OFF_ES);
    float*  invq    = (float*) (ws + OFF_INVQ);
    int*    pos     = (int*)   (ws + OFF_POS);
    float*  coef    = (float*) (ws + OFF_COEF);
    int*    rlist   = (int*)   (ws + OFF_RLIST);
    int*    clist   = (int*)   (ws + OFF_CLIST);
    double* pninv   = (double*)(ws + OFF_PNINV);
    float*  proto   = (float*) (ws + OFF_PROTO);
    short*  Phi     = (short*) (ws + OFF_PHI);
    short*  APhi    = (short*) (ws + OFF_APHI);
    float*  Sred    = (float*) (ws + OFF_SRED);
    float*  APpart  = (float*) (ws + OFF_APPART);
    float*  Part    = (float*) (ws + OFF_PART);

    // runtime k-split count from available scratch (pow2, 1..16)
    int nks = 1;
    if (ws_size > (size_t)OFF_PART + SLICE_BYTES) {
        size_t avail = (ws_size - OFF_PART) / SLICE_BYTES;
        nks = avail >= 16 ? 16 : (int)avail;
        while (nks & (nks - 1)) nks &= nks - 1;
    }

    hipMemsetAsync(ws, 0, ZERO_BYTES, stream);

    k_proto <<<NPAD, 256, 0, stream>>>(x, proto, Phi, es, pninv);
    switch (nks) {
        case 16: k_gemm<16,true><<<dim3(118, 16), 256, 0, stream>>>(x, Phi, Part, nq2); break;
        case 8:  k_gemm<8, true><<<dim3(118, 8),  256, 0, stream>>>(x, Phi, Part, nq2); break;
        case 4:  k_gemm<4, true><<<dim3(118, 4),  256, 0, stream>>>(x, Phi, Part, nq2); break;
        case 2:  k_gemm<2, true><<<dim3(118, 2),  256, 0, stream>>>(x, Phi, Part, nq2); break;
        default: k_gemm<1, true><<<dim3(118, 1),  256, 0, stream>>>(x, Phi, Part, nq2); break;
    }
    k_reduce1<<<826, 256, 0, stream>>>(Part, Sred, nks);
    k_argmax <<<30, 256, 0, stream>>>(Sred, nq2, coef, invq, pos, ccnt, clist, rcnt, rlist);
    k_refine <<<512, 256, 0, stream>>>(x, proto, pninv, Sred, invq, coef, pos, ccnt, clist, rcnt, rlist);
    k_adapt  <<<dim3(8, NCLS, 4), 128, 0, stream>>>(x, coef, ccnt, clist, APpart);
    k_apnorm <<<NPAD, 256, 0, stream>>>(APpart, proto, es, APhi);
    switch (nks) {
        case 16: k_gemm<16,false><<<dim3(118, 16), 256, 0, stream>>>(x, APhi, Part, nq2); break;
        case 8:  k_gemm<8, false><<<dim3(118, 8),  256, 0, stream>>>(x, APhi, Part, nq2); break;
        case 4:  k_gemm<4, false><<<dim3(118, 4),  256, 0, stream>>>(x, APhi, Part, nq2); break;
        case 2:  k_gemm<2, false><<<dim3(118, 2),  256, 0, stream>>>(x, APhi, Part, nq2); break;
        default: k_gemm<1, false><<<dim3(118, 1),  256, 0, stream>>>(x, APhi, Part, nq2); break;
    }
    k_reduce2<<<733, 256, 0, stream>>>(Part, invq, tao, (float*)d_out, nks);
}